// Round 8
// baseline (135.484 us; speedup 1.0000x reference)
//
#include <hip/hip_runtime.h>
#include <math.h>

// PCNN recurrence v10: time-split two-phase, 4 waves/SIMD, NO inline-asm VMEM.
// (Resubmission — round 7 bench died on container infra, kernel never ran.)
//
// v8/v9 post-mortem: asm "=v" loads + hand-counted vmcnt are fragile (regalloc
// may copy in-flight dest regs with no ordering vs my waits) and the whole
// counted-wait arc bought <=2us. Abandoned. v9 also had a real bug: 3 elems/
// lane makes partial-OOB lanes (3 does not divide 2), and one clamped base
// shifts the load window for in-bounds elements.
//
// Surviving facts: kernel ~39-44us in every variant; BW floor ~21us; issue
// floor ~11us; VALUBusy ~47% == 2 waves/SIMD with half the issue slots idle.
// Occupancy is the only untested axis. The halo must cover the steps a wave
// runs without communication, so: split T=64 into 2 phases of 32 steps.
//   chunk = 64 stored cols, halo 32 each side -> region 128 = 2 elems/lane
//   (float2, even alignment -> no partial-OOB lanes, structurally).
//   4096 waves/phase = 1024 blocks x 4 = 4 waves/SIMD (2x TLP).
// Between phases: f,l,e state (3.1MB) via d_ws; y re-read from out row 31.
// Correctness margin (1 col/step propagation): region-edge corruption reaches
// stored col 32 at row 34 (phase1 ends at 31) and row 66 (phase2 ends at 63).
// Phase-1 state saved after row 31 is uncorrupted for stored cols. Exact.
// Fallback: if ws_size < 3.2MB, launch the verified v4 kernel (43.7us).

#define TT 64
#define LL 8192
#define BB 32
#define SLT (BB * LL)                    // one state plane (floats)
#define WS_NEED ((size_t)3 * SLT * 4)    // f,l,e planes in bytes

typedef float v2f __attribute__((ext_vector_type(2)));

__device__ __forceinline__ float dpp_shr1(float v) {
    // lane i <- lane i-1; lane 0 <- 0 (bound_ctrl). WAVE_SHR1=0x138.
    return __int_as_float(__builtin_amdgcn_update_dpp(
        0, __float_as_int(v), 0x138, 0xF, 0xF, true));
}
__device__ __forceinline__ float dpp_shl1(float v) {
    // lane i <- lane i+1; lane 63 <- 0 (bound_ctrl). WAVE_SHL1=0x130.
    return __int_as_float(__builtin_amdgcn_update_dpp(
        0, __float_as_int(v), 0x130, 0xF, 0xF, true));
}
__device__ __forceinline__ float rdlane(float v, int l) {
    return __int_as_float(__builtin_amdgcn_readlane(__float_as_int(v), l));
}
__device__ __forceinline__ float fsig_neg(float z) {
    // sigmoid(u-e) with z = e-u: 1/(1+exp(z)); z=+inf -> exactly 0.
    return __fdividef(1.0f, 1.0f + __expf(z));
}

// ---------------- two-phase kernel (primary path) ----------------
template <int PHASE>   // 0: rows 0..31, cold init, saves state; 1: rows 32..63
__global__ __launch_bounds__(256, 4) void pcnn_ph(
    const float* __restrict__ x, const float* __restrict__ wptr,
    float* __restrict__ out, float* __restrict__ ws)
{
    const int lane  = threadIdx.x & 63;
    const int tile  = blockIdx.x * 4 + (threadIdx.x >> 6);  // 4096 tiles
    const int chunk = tile & 127;                           // 128 chunks
    const int b     = tile >> 7;                            // 32 batches

    const float w0 = wptr[0], w1 = wptr[1], w2 = wptr[2];
    const float df = 0.90483741803595957f;  // exp(-0.1)
    const float dl = 0.36787944117144233f;  // exp(-1)
    const float de = 0.36787944117144233f;

    const int c0 = chunk * 64 - 32 + 2 * lane;   // even; region idx = 2*lane
    const bool vz = ((unsigned)c0 < (unsigned)LL);  // whole float2 in/out
    const int cc = min(max(c0, 0), LL - 2);         // safe load col (even)
    const bool mid = (lane >= 16) && (lane < 48);   // stored cols: region 32..95

    const size_t base = (size_t)b * (TT * LL) + (size_t)(PHASE * 32) * LL;
    const float* xrow = x + base + cc;              // phase row 0, load col
    float* orow = out + base + c0;                  // deref'd only when mid

    const float INF = __builtin_inff();
    v2f f, l, e, y;
    if (PHASE == 0) {
        f = (v2f){0.f, 0.f};  l = f;  y = f;
        const float ev = vz ? 10.f : INF;  // OOB: y pinned to 0 forever
        e = (v2f){ev, ev};
    } else {
        const size_t sb = (size_t)b * LL + cc;
        f = *(const v2f*)(ws + 0 * (size_t)SLT + sb);
        l = *(const v2f*)(ws + 1 * (size_t)SLT + sb);
        e = *(const v2f*)(ws + 2 * (size_t)SLT + sb);
        y = *(const v2f*)(out + (size_t)b * (TT * LL) + 31 * (size_t)LL + cc);
        if (!vz) {                      // clamped loads read col 0/8190 state:
            e = (v2f){INF, INF};        // pin y=0 forever (reference zero-pad)
            y = (v2f){0.f, 0.f};        // conv feed from OOB col must be 0
        }                               // f,l garbage-but-finite: never visible
    }

    // 4-deep ring, plain compiler loads — TLP (4 waves/SIMD) hides latency.
    v2f ring[4];
    #pragma unroll
    for (int j = 0; j < 4; ++j)
        ring[j] = *(const v2f*)(xrow + (size_t)j * LL);

    for (int t = 0; t < 32; t += 4) {
        #pragma unroll
        for (int j = 0; j < 4; ++j) {
            const v2f xa = ring[j];
            int rr = t + 4 + j;  rr = rr > 31 ? 31 : rr;   // clamped refill
            ring[j] = *(const v2f*)(xrow + (size_t)rr * LL);

            // neighbor exchange (old y): contiguous layout -> pure DPP.
            // lane0/lane63 edges get 0 = region edge (halo margin proven).
            const float yl = dpp_shr1(y.y);   // left of elem .x
            const float yr = dpp_shl1(y.x);   // right of elem .y
            const v2f sl = {yl, y.x}, sr = {y.y, yr};

            f = df * f + xa + (w0 * sl + w1 * y + w2 * sr);
            l = dl * l + (sl + sr);
            const v2f u = f * (1.0f + 0.5f * l);
            e = de * e + 10.0f * y;           // uses OLD y
            const v2f z = e - u;              // sigmoid(u-e) = 1/(1+exp(z))
            y.x = fsig_neg(z.x);
            y.y = fsig_neg(z.y);

            if (mid) *(v2f*)orow = y;         // 256B contiguous per wave-row
            orow += LL;
        }
    }

    if (PHASE == 0 && mid) {                  // save state for stored cols
        const size_t sb = (size_t)b * LL + c0;
        *(v2f*)(ws + 0 * (size_t)SLT + sb) = f;
        *(v2f*)(ws + 1 * (size_t)SLT + sb) = l;
        *(v2f*)(ws + 2 * (size_t)SLT + sb) = e;
    }
}

// ---------------- fallback: verified v4 kernel (43.7us) ----------------
#define CC4 128
#define HH4 64
#define NCHUNK4 64
#define DEPTH4 16

__global__ __launch_bounds__(256) void pcnn_fb(
    const float* __restrict__ x, const float* __restrict__ wptr,
    float* __restrict__ out)
{
    const int lane = threadIdx.x & 63;
    const int tile = blockIdx.x * 4 + (threadIdx.x >> 6);
    const int chunk = tile & (NCHUNK4 - 1);
    const int b     = tile >> 6;

    const float w0 = wptr[0], w1 = wptr[1], w2 = wptr[2];
    const float df = 0.90483741803595957f;
    const float dl = 0.36787944117144233f;
    const float de = 0.36787944117144233f;

    const int r0 = 2 * lane;
    const int c0 = chunk * CC4 - HH4 + r0;
    const int c1 = c0 + 128;
    const bool vz0 = ((unsigned)c0 < (unsigned)LL);
    const bool vz1 = ((unsigned)c1 < (unsigned)LL);
    const int cc0 = min(max(c0, 0), LL - 2);
    const int cc1 = min(max(c1, 0), LL - 2);

    const float* xbase = x + (size_t)b * TT * LL;
    const float* xp0 = xbase + cc0;
    const float* xp1 = xbase + cc1;

    const bool lo = (lane < 32);
    float* op = out + (size_t)b * TT * LL + (lo ? c1 : c0);

    const bool is0  = (lane == 0);
    const bool is63 = (lane == 63);

    v2f p0[DEPTH4], p1[DEPTH4];
    #pragma unroll
    for (int j = 0; j < DEPTH4; ++j) {
        p0[j] = *(const v2f*)(xp0 + (size_t)j * LL);
        p1[j] = *(const v2f*)(xp1 + (size_t)j * LL);
    }

    const float INF = __builtin_inff();
    v2f f0 = {0.f, 0.f}, f1 = {0.f, 0.f};
    v2f l0 = {0.f, 0.f}, l1 = {0.f, 0.f};
    v2f e0, e1;
    e0.x = vz0 ? 10.f : INF;  e0.y = e0.x;
    e1.x = vz1 ? 10.f : INF;  e1.y = e1.x;
    v2f y0 = {0.f, 0.f}, y1 = {0.f, 0.f};

    auto step = [&](v2f xa, v2f xb) {
        float yl0 = dpp_shr1(y0.y);
        float rl1 = dpp_shr1(y1.y);
        float yl1 = is0 ? rdlane(y0.y, 63) : rl1;
        float rr0 = dpp_shl1(y0.x);
        float yr0 = is63 ? rdlane(y1.x, 0) : rr0;
        float yr1 = dpp_shl1(y1.x);

        v2f sl0 = {yl0, y0.x}, sr0 = {y0.y, yr0};
        v2f sl1 = {yl1, y1.x}, sr1 = {y1.y, yr1};

        f0 = df * f0 + xa + (w0 * sl0 + w1 * y0 + w2 * sr0);
        f1 = df * f1 + xb + (w0 * sl1 + w1 * y1 + w2 * sr1);
        l0 = dl * l0 + (sl0 + sr0);
        l1 = dl * l1 + (sl1 + sr1);
        v2f u0 = f0 * (1.0f + 0.5f * l0);
        v2f u1 = f1 * (1.0f + 0.5f * l1);
        e0 = de * e0 + 10.0f * y0;
        e1 = de * e1 + 10.0f * y1;
        v2f z0 = e0 - u0, z1 = e1 - u1;
        y0.x = fsig_neg(z0.x);  y0.y = fsig_neg(z0.y);
        y1.x = fsig_neg(z1.x);  y1.y = fsig_neg(z1.y);

        v2f yst;
        yst.x = lo ? y1.x : y0.x;
        yst.y = lo ? y1.y : y0.y;
        *(v2f*)op = yst;
        op += LL;
    };

    const float* xl0 = xp0 + DEPTH4 * (size_t)LL;
    const float* xl1 = xp1 + DEPTH4 * (size_t)LL;

    for (int t = 0; t < TT; t += DEPTH4) {
        const bool live = (t + 2 * DEPTH4 <= TT);
        const float* a0 = live ? xl0 : xp0;
        const float* a1 = live ? xl1 : xp1;
        const size_t st = live ? (size_t)LL : 0;
        #pragma unroll
        for (int j = 0; j < DEPTH4; ++j) {
            step(p0[j], p1[j]);
            p0[j] = *(const v2f*)(a0 + (size_t)j * st);
            p1[j] = *(const v2f*)(a1 + (size_t)j * st);
        }
        xl0 += DEPTH4 * (size_t)LL;
        xl1 += DEPTH4 * (size_t)LL;
    }
}

extern "C" void kernel_launch(void* const* d_in, const int* in_sizes, int n_in,
                              void* d_out, int out_size, void* d_ws, size_t ws_size,
                              hipStream_t stream) {
    const float* x = (const float*)d_in[0];
    const float* w = (const float*)d_in[1];
    float* out = (float*)d_out;
    if (ws_size >= WS_NEED && d_ws != nullptr) {
        float* ws = (float*)d_ws;
        // 1024 blocks x 4 waves per phase = 4096 waves = 4/SIMD.
        pcnn_ph<0><<<dim3(1024), dim3(256), 0, stream>>>(x, w, out, ws);
        pcnn_ph<1><<<dim3(1024), dim3(256), 0, stream>>>(x, w, out, ws);
    } else {
        pcnn_fb<<<dim3(512), dim3(256), 0, stream>>>(x, w, out);
    }
}

// Round 10
// 119.995 us; speedup vs baseline: 1.1291x; 1.1291x over previous
//
#include <hip/hip_runtime.h>
#include <math.h>

// PCNN recurrence v12: x staged via global_load_lds (no VGPR dest -> no
// regalloc hazard), counted vmcnt pipeline, plain compiler stores.
//
// Model correction (v10 numbers): with an exactly-resident grid, kernel time
// = steps x per-wave step-wall (v7: 64x1464cyc=39us; v10: 32x2000=26.6us).
// TLP cannot help; only the wall can shrink. Issue ~160cyc -> ~1300cyc of
// stall lives in the VMEM path. v12 removes the load path from the chain:
//  - x rows -> LDS via __builtin_amdgcn_global_load_lds (16B/lane, 1 op/row):
//    dest is LDS (wave-uniform base + lane*16), no dest register exists.
//  - 16-slot LDS ring, prefetch distance 8 rows; 1 gll + 1 plain store per
//    step -> exact counted waits: head 7..14, steady 14, tail 13..7. Never
//    drains, no barriers (waves independent).
//  - per-step x read = ds_read_b64 x2 (compiler-visible, precise lgkmcnt,
//    ~100cyc, 2-way bank aliasing = free).
//  - compute core + merged store = v7 verbatim (proven correct/fast).
// If still ~flat: load path exonerated -> store back-pressure is the wall.

#define TT 64
#define LL 8192
#define CC 128
#define HH 64
#define NCHUNK 64      // LL / CC
#define RING 16        // LDS ring slots (rows)
#define PFD 8          // prefetch distance (rows)

typedef float v2f __attribute__((ext_vector_type(2)));

__device__ __forceinline__ float dpp_shr1(float v) {
    // lane i <- lane i-1; lane 0 <- 0 (bound_ctrl). WAVE_SHR1=0x138.
    return __int_as_float(__builtin_amdgcn_update_dpp(
        0, __float_as_int(v), 0x138, 0xF, 0xF, true));
}
__device__ __forceinline__ float dpp_shl1(float v) {
    // lane i <- lane i+1; lane 63 <- 0 (bound_ctrl). WAVE_SHL1=0x130.
    return __int_as_float(__builtin_amdgcn_update_dpp(
        0, __float_as_int(v), 0x130, 0xF, 0xF, true));
}
__device__ __forceinline__ float rdlane(float v, int l) {
    return __int_as_float(__builtin_amdgcn_readlane(__float_as_int(v), l));
}
__device__ __forceinline__ float fsig_neg(float z) {
    // sigmoid(u-e) with z = e-u: 1/(1+exp(z)); z=+inf -> exactly 0.
    return __fdividef(1.0f, 1.0f + __expf(z));
}
// global -> LDS direct copy, 16B per lane (64 lanes = 1KB row segment).
// LDS dest must be wave-uniform; global src is per-lane. CK-style casts.
__device__ __forceinline__ void gll16(const float* g, float* l) {
    __builtin_amdgcn_global_load_lds(
        (const __attribute__((address_space(1))) void*)(uintptr_t)(g),
        (__attribute__((address_space(3))) void*)(uintptr_t)(l),
        16, 0, 0);
}
#define WAITV(n) do { \
    asm volatile("s_waitcnt vmcnt(" #n ")" ::: "memory"); \
    __builtin_amdgcn_sched_barrier(0); } while (0)

__global__ __launch_bounds__(256) void pcnn12_kernel(
    const float* __restrict__ x, const float* __restrict__ wptr,
    float* __restrict__ out)
{
    const int lane = threadIdx.x & 63;
    const int wid  = threadIdx.x >> 6;
    const int tile = blockIdx.x * 4 + wid;       // 2048 wave-tiles
    const int chunk = tile & (NCHUNK - 1);
    const int b     = tile >> 6;

    __shared__ float xs[4][RING][256];           // 64KB: per-wave 16 rows

    const float w0 = wptr[0], w1 = wptr[1], w2 = wptr[2];
    const float df = 0.90483741803595957f;  // exp(-0.1)
    const float dl = 0.36787944117144233f;  // exp(-1)
    const float de = 0.36787944117144233f;

    const int regstart = chunk * CC - HH;        // region col 0 (may be <0)
    // gll source granule (16B) per lane: region idx 4*lane..4*lane+3.
    // Clamped for edge chunks -> garbage lands only in OOB region slots,
    // which are e=+inf pinned and never used.
    int g = regstart + 4 * lane;
    g = min(max(g, 0), LL - 4);
    const float* gsrc = x + (size_t)b * TT * LL + g;

    // compute cols (v7 layout): slot0 = region idx 2*lane, slot1 = +128
    const int c0 = regstart + 2 * lane;
    const int c1 = c0 + 128;
    const bool vz0 = ((unsigned)c0 < (unsigned)LL);
    const bool vz1 = ((unsigned)c1 < (unsigned)LL);

    // merged store (v7): lanes 0..31 write slot1, 32..63 slot0 — contiguous
    // 512B per wave-row, always in-bounds, unconditional.
    const bool lo = (lane < 32);
    float* op = out + (size_t)b * TT * LL + (lo ? c1 : c0);

    const bool is0  = (lane == 0);
    const bool is63 = (lane == 63);

    // prologue: stage rows 0..7 (8 gll ops in flight)
    #pragma unroll
    for (int j = 0; j < PFD; ++j)
        gll16(gsrc + (size_t)j * LL, &xs[wid][j][0]);

    const float INF = __builtin_inff();
    v2f f0 = {0.f, 0.f}, f1 = {0.f, 0.f};
    v2f l0 = {0.f, 0.f}, l1 = {0.f, 0.f};
    // OOB cols: e=+inf -> y=0 exactly forever (reference zero-pad semantics)
    v2f e0, e1;
    e0.x = vz0 ? 10.f : INF;  e0.y = e0.x;
    e1.x = vz1 ? 10.f : INF;  e1.y = e1.x;
    v2f y0 = {0.f, 0.f}, y1 = {0.f, 0.f};

    auto stepf = [&](v2f xa, v2f xc) {
        // neighbor exchange (old y) — pure VALU
        float yl0 = dpp_shr1(y0.y);                // lane0 -> 0 (region edge)
        float rl1 = dpp_shr1(y1.y);
        float yl1 = is0 ? rdlane(y0.y, 63) : rl1;  // slot1 left of lane0
        float rr0 = dpp_shl1(y0.x);
        float yr0 = is63 ? rdlane(y1.x, 0) : rr0;  // slot0 right of lane63
        float yr1 = dpp_shl1(y1.x);                // lane63 -> 0 (region edge)

        v2f sl0 = {yl0, y0.x}, sr0 = {y0.y, yr0};
        v2f sl1 = {yl1, y1.x}, sr1 = {y1.y, yr1};

        f0 = df * f0 + xa + (w0 * sl0 + w1 * y0 + w2 * sr0);
        f1 = df * f1 + xc + (w0 * sl1 + w1 * y1 + w2 * sr1);
        l0 = dl * l0 + (sl0 + sr0);
        l1 = dl * l1 + (sl1 + sr1);
        v2f u0 = f0 * (1.0f + 0.5f * l0);
        v2f u1 = f1 * (1.0f + 0.5f * l1);
        e0 = de * e0 + 10.0f * y0;                 // uses OLD y
        e1 = de * e1 + 10.0f * y1;
        v2f z0 = e0 - u0, z1 = e1 - u1;            // sigmoid(u-e)=1/(1+exp(z))
        y0.x = fsig_neg(z0.x);  y0.y = fsig_neg(z0.y);
        y1.x = fsig_neg(z1.x);  y1.y = fsig_neg(z1.y);

        v2f yst;
        yst.x = lo ? y1.x : y0.x;
        yst.y = lo ? y1.y : y0.y;
        *(v2f*)op = yst;                           // plain store, no wait ever
        op += LL;
    };

    // Wait math (2 VMEM ops/step: 1 gll + 1 store; vmcnt retires in order):
    //  head t<8:  row-t gll has (7-t) prologue + 2t step ops younger = 7+t
    //             -> WAITV(7+t) forces it retired.
    //  steady:    row-t gll (issued step t-8) has 7x2=14..15 younger
    //             -> WAITV(14).
    //  tail t>56: gll stream stopped at t=55 -> younger shrinks by 1/step
    //             -> 13,12,...,7.
#define STEP_G(T_, W_) do { WAITV(W_);                                   \
        v2f xa_ = *(const v2f*)&xs[wid][(T_) & 15][2 * lane];            \
        v2f xc_ = *(const v2f*)&xs[wid][(T_) & 15][128 + 2 * lane];      \
        gll16(gsrc + (size_t)((T_) + PFD) * LL,                          \
              &xs[wid][((T_) + PFD) & 15][0]);                           \
        stepf(xa_, xc_); } while (0)
#define STEP_N(T_, W_) do { WAITV(W_);                                   \
        v2f xa_ = *(const v2f*)&xs[wid][(T_) & 15][2 * lane];            \
        v2f xc_ = *(const v2f*)&xs[wid][(T_) & 15][128 + 2 * lane];      \
        stepf(xa_, xc_); } while (0)

    STEP_G(0, 7);  STEP_G(1, 8);  STEP_G(2, 9);  STEP_G(3, 10);
    STEP_G(4, 11); STEP_G(5, 12); STEP_G(6, 13); STEP_G(7, 14);

    for (int t = 8; t <= 55; ++t) {   // refills rows 16..63
        STEP_G(t, 14);
    }

    STEP_N(56, 14);
    STEP_N(57, 13); STEP_N(58, 12); STEP_N(59, 11); STEP_N(60, 10);
    STEP_N(61, 9);  STEP_N(62, 8);  STEP_N(63, 7);
#undef STEP_G
#undef STEP_N
}

extern "C" void kernel_launch(void* const* d_in, const int* in_sizes, int n_in,
                              void* d_out, int out_size, void* d_ws, size_t ws_size,
                              hipStream_t stream) {
    const float* x = (const float*)d_in[0];
    const float* w = (const float*)d_in[1];
    float* out = (float*)d_out;
    // 2048 wave-tiles = 512 blocks x 4 waves; 64KB LDS -> 2 blocks/CU,
    // exactly-resident grid. No barriers, waves independent.
    pcnn12_kernel<<<dim3(512), dim3(256), 0, stream>>>(x, w, out);
}